// Round 5
// baseline (9408.073 us; speedup 1.0000x reference)
//
#include <hip/hip_runtime.h>
#include <hip/hip_bf16.h>
#include <math.h>

// Problem constants (fixed by the reference)
#define T_STEPS 6
#define N_NODES 50000
#define IN_DIM  256
#define HID     256
#define R_REL   4
#define E_EDGES 800000
#define G3      768    // 3*HID
#define MPAD    50048  // N rounded up to 128
#define NTR     24     // T*R
#define ETOT    19200000
#define NTOT    1200000   // NTR*N
#define NBKT_R  782       // ceil(N/64) buckets of 64 rows per (t,r)
#define NBKT_TOT 18768    // NBKT_R * NTR

typedef unsigned short ushort_t;
typedef __bf16 bf16x8 __attribute__((ext_vector_type(8)));
typedef float  f32x4  __attribute__((ext_vector_type(4)));

// round-to-nearest-even fp32 -> bf16 (bit-level, self-contained)
__device__ __forceinline__ ushort_t f2bf(float f) {
    unsigned u = __float_as_uint(f);
    u = (u + 0x7FFF + ((u >> 16) & 1)) >> 16;
    return (ushort_t)u;
}
__device__ __forceinline__ float bf2f(ushort_t b) {
    return __uint_as_float(((unsigned)b) << 16);
}
__device__ __forceinline__ void bsplit(float v, ushort_t& h, ushort_t& l) {
    h = f2bf(v);
    l = f2bf(v - bf2f(h));
}

// ---------------------------------------------------------------------------
// Weight prep: dst (hi/lo bf16, [Nc][K] row-major = B^T) from fp32 src.
__global__ void prep_bt(const float* __restrict__ src, ushort_t* __restrict__ hi,
                        ushort_t* __restrict__ lo, int K, int Nc, int transposed) {
    int idx = blockIdx.x * blockDim.x + threadIdx.x;
    if (idx >= K * Nc) return;
    int n = idx / K, k = idx % K;
    float v = transposed ? src[(size_t)n * K + k] : src[(size_t)k * Nc + n];
    ushort_t h, l;
    bsplit(v, h, l);
    hi[idx] = h;
    lo[idx] = l;
}

// ---------------------------------------------------------------------------
// Bucketed CSR build. Bucket = (tr, row>>6): 64-row buckets, NBKT_TOT total.
// Step 1: bucket histogram
__global__ void bucket_hist(const int* __restrict__ row, int* __restrict__ bcounts) {
    int ge = blockIdx.x * blockDim.x + threadIdx.x;
    if (ge >= ETOT) return;
    int tr = ge / E_EDGES;
    atomicAdd(&bcounts[tr * NBKT_R + (row[ge] >> 6)], 1);
}

// scan step 1: per-block (1024) exclusive scan; emit block sums
__global__ __launch_bounds__(1024)
void scan1(const int* __restrict__ counts, int* __restrict__ starts,
           int* __restrict__ bsums, int n) {
    __shared__ int temp[1024];
    int i = blockIdx.x * 1024 + threadIdx.x;
    int v = (i < n) ? counts[i] : 0;
    temp[threadIdx.x] = v;
    __syncthreads();
#pragma unroll
    for (int off = 1; off < 1024; off <<= 1) {
        int t = (threadIdx.x >= (unsigned)off) ? temp[threadIdx.x - off] : 0;
        __syncthreads();
        temp[threadIdx.x] += t;
        __syncthreads();
    }
    int incl = temp[threadIdx.x];
    if (i < n) starts[i] = incl - v;
    if (threadIdx.x == 1023) bsums[blockIdx.x] = incl;
}

// scan step 2: single-block exclusive scan of block sums
__global__ __launch_bounds__(1024)
void scan_block(const int* __restrict__ counts, int* __restrict__ starts, int n) {
    __shared__ int temp[1024];
    __shared__ int carry;
    if (threadIdx.x == 0) carry = 0;
    __syncthreads();
    for (int base = 0; base < n; base += 1024) {
        int i = base + (int)threadIdx.x;
        int v = (i < n) ? counts[i] : 0;
        temp[threadIdx.x] = v;
        __syncthreads();
#pragma unroll
        for (int off = 1; off < 1024; off <<= 1) {
            int t = (threadIdx.x >= (unsigned)off) ? temp[threadIdx.x - off] : 0;
            __syncthreads();
            temp[threadIdx.x] += t;
            __syncthreads();
        }
        int incl = temp[threadIdx.x];
        if (i < n) starts[i] = carry + incl - v;
        __syncthreads();
        if (threadIdx.x == 1023) carry += incl;
        __syncthreads();
    }
    if (threadIdx.x == 0) starts[n] = carry;
}

// scan step 3: add block offsets; write sentinel
__global__ __launch_bounds__(1024)
void scan3(int* __restrict__ starts, const int* __restrict__ bsumsX, int n) {
    int i = blockIdx.x * 1024 + threadIdx.x;
    if (i < n) starts[i] += bsumsX[blockIdx.x];
    if (i == 0) starts[n] = ETOT;
}

// Step 2: scatter packed records into bucket-sorted order (line-local writes:
// live cache-line set = NBKT_TOT * 128B = 2.4 MB, fits per-XCD L2)
__global__ void bucket_fill(const int* __restrict__ row, const int* __restrict__ col,
                            const float* __restrict__ w, const int* __restrict__ bstarts,
                            int* __restrict__ bcursor, int2* __restrict__ brec) {
    int ge = blockIdx.x * blockDim.x + threadIdx.x;
    if (ge >= ETOT) return;
    int rr = row[ge];
    int key = (ge / E_EDGES) * NBKT_R + (rr >> 6);
    int pos = bstarts[key] + atomicAdd(&bcursor[key], 1);
    brec[pos] = make_int2(col[ge] | ((rr & 63) << 16), __float_as_int(w[ge]));
}

// Step 3: per-bucket row placement. One block per bucket: count 64 rows in LDS,
// local scan -> per-row global starts[]; re-scatter records into exact CSR
// order (writes land in an ~8KB window -> line-local).
__global__ __launch_bounds__(256)
void csr_place(const int2* __restrict__ brec, const int* __restrict__ bstarts,
               int* __restrict__ starts, int2* __restrict__ colw) {
    __shared__ int cnt[64], rstart[64];
    int b = blockIdx.x, tid = threadIdx.x;
    int bstart = bstarts[b], bend = bstarts[b + 1];
    if (tid < 64) cnt[tid] = 0;
    __syncthreads();
    for (int e = bstart + tid; e < bend; e += 256)
        atomicAdd(&cnt[(brec[e].x >> 16) & 63], 1);
    __syncthreads();
    if (tid == 0) {
        int run = 0;
#pragma unroll
        for (int i = 0; i < 64; ++i) { rstart[i] = run; run += cnt[i]; }
        if (b == 0) starts[NTOT] = ETOT;   // row-level sentinel
    }
    __syncthreads();
    int tr = b / NBKT_R, bb = b % NBKT_R;
    if (tid < 64) {
        int g = bb * 64 + tid;
        if (g < N_NODES) starts[tr * N_NODES + g] = bstart + rstart[tid];
        cnt[tid] = 0;
    }
    __syncthreads();
    for (int e = bstart + tid; e < bend; e += 256) {
        int2 rec = brec[e];
        int rowlo = (rec.x >> 16) & 63;
        int pos = bstart + rstart[rowlo] + atomicAdd(&cnt[rowlo], 1);
        colw[pos] = make_int2(rec.x & 0xFFFF, rec.y);
    }
}

// ---------------------------------------------------------------------------
// Aggregation, batched over the 4 relations of one t (blockIdx.y = r).
// One wave per destination row; gather x rows, accumulate, write bf16 hi/lo.
__global__ void csr_agg_t(const float* __restrict__ x, const int2* __restrict__ colw,
                          const int* __restrict__ startsT,
                          ushort_t* __restrict__ tmp_hi, ushort_t* __restrict__ tmp_lo,
                          float* __restrict__ rowsum) {
    int wid  = (blockIdx.x * blockDim.x + threadIdx.x) >> 6;
    int lane = threadIdx.x & 63;
    int r    = blockIdx.y;
    if (wid >= N_NODES) return;
    int s0 = startsT[r * N_NODES + wid], s1 = startsT[r * N_NODES + wid + 1];
    float4 acc = make_float4(0.f, 0.f, 0.f, 0.f);
    float wsum = 0.f;
    for (int e = s0; e < s1; ++e) {
        int2 cw = colw[e];
        float we = __int_as_float(cw.y);
        float4 xv = ((const float4*)(x + (size_t)cw.x * 256))[lane];
        acc.x = fmaf(we, xv.x, acc.x);
        acc.y = fmaf(we, xv.y, acc.y);
        acc.z = fmaf(we, xv.z, acc.z);
        acc.w = fmaf(we, xv.w, acc.w);
        wsum += we;
    }
    ushort4 hv, lv;
    bsplit(acc.x, hv.x, lv.x);
    bsplit(acc.y, hv.y, lv.y);
    bsplit(acc.z, hv.z, lv.z);
    bsplit(acc.w, hv.w, lv.w);
    size_t o = ((size_t)r * MPAD + wid) * 256 + lane * 4;
    *(ushort4*)(tmp_hi + o) = hv;
    *(ushort4*)(tmp_lo + o) = lv;
    if (lane == 0) rowsum[r * MPAD + wid] = wsum;
}

// ---------------------------------------------------------------------------
// MFMA GEMM, hi/lo split: C = (Ahi+Alo) @ (Bhi+Blo), dropping lo*lo.
// A row-major [M][256] bf16; B transposed [Nc][256] bf16.
// Tile 128x128, BK=64, 4 waves (2x2). blockIdx.z selects batched operand set.
__global__ __launch_bounds__(256, 2)
void mfma_gemm(const ushort_t* __restrict__ Ahi, const ushort_t* __restrict__ Alo,
               const ushort_t* __restrict__ Bthi, const ushort_t* __restrict__ Btlo,
               float* __restrict__ C, int M, int Nc,
               const float* __restrict__ bias, const float* __restrict__ rowscale,
               int do_relu, size_t aZ, size_t bZ, size_t cZ, int biasZ, int rsZ) {
    int z = blockIdx.z;
    Ahi  += (size_t)z * aZ;  Alo  += (size_t)z * aZ;
    Bthi += (size_t)z * bZ;  Btlo += (size_t)z * bZ;
    C    += (size_t)z * cZ;
    if (bias)     bias     += (size_t)z * biasZ;
    if (rowscale) rowscale += (size_t)z * rsZ;

    __shared__ __align__(16) char smem[65536];
    const int AHI = 0, ALO = 16384, BHI = 32768, BLO = 49152;
    int tid = threadIdx.x;
    int m0 = blockIdx.x * 128, n0 = blockIdx.y * 128;
    int lane = tid & 63, wid = tid >> 6;
    int wr = wid >> 1, wc = wid & 1;
    int lr = lane & 15, lk = lane >> 4;
    int xorv = (lr & 7) << 4;

    f32x4 acc[4][4];
#pragma unroll
    for (int i = 0; i < 4; ++i)
#pragma unroll
        for (int j = 0; j < 4; ++j)
            acc[i][j] = (f32x4){0.f, 0.f, 0.f, 0.f};

    for (int kt = 0; kt < 4; ++kt) {
        int k0 = kt * 64;
        __syncthreads();
#pragma unroll
        for (int i = 0; i < 4; ++i) {
            int c = tid + i * 256;          // 0..1023 chunk id (16B chunks)
            int row = c >> 3, slot = c & 7; // 128 rows x 8 slots
            int ldsoff = row * 128 + ((slot * 16) ^ ((row & 7) << 4));
            size_t ga = (size_t)(m0 + row) * 256 + k0 + slot * 8;
            size_t gb = (size_t)(n0 + row) * 256 + k0 + slot * 8;
            *(int4*)(smem + AHI + ldsoff) = *(const int4*)(Ahi + ga);
            *(int4*)(smem + ALO + ldsoff) = *(const int4*)(Alo + ga);
            *(int4*)(smem + BHI + ldsoff) = *(const int4*)(Bthi + gb);
            *(int4*)(smem + BLO + ldsoff) = *(const int4*)(Btlo + gb);
        }
        __syncthreads();
#pragma unroll
        for (int kk2 = 0; kk2 < 2; ++kk2) {
            int kb = (kk2 * 64 + lk * 16) ^ xorv;
            bf16x8 ah[4], al[4], bh[4], bl[4];
#pragma unroll
            for (int f = 0; f < 4; ++f) {
                int ra = (wr * 64 + f * 16 + lr) * 128 + kb;
                int rb = (wc * 64 + f * 16 + lr) * 128 + kb;
                ah[f] = *(const bf16x8*)(smem + AHI + ra);
                al[f] = *(const bf16x8*)(smem + ALO + ra);
                bh[f] = *(const bf16x8*)(smem + BHI + rb);
                bl[f] = *(const bf16x8*)(smem + BLO + rb);
            }
#pragma unroll
            for (int fm = 0; fm < 4; ++fm)
#pragma unroll
                for (int fn = 0; fn < 4; ++fn) {
                    acc[fm][fn] = __builtin_amdgcn_mfma_f32_16x16x32_bf16(ah[fm], bh[fn], acc[fm][fn], 0, 0, 0);
                    acc[fm][fn] = __builtin_amdgcn_mfma_f32_16x16x32_bf16(ah[fm], bl[fn], acc[fm][fn], 0, 0, 0);
                    acc[fm][fn] = __builtin_amdgcn_mfma_f32_16x16x32_bf16(al[fm], bh[fn], acc[fm][fn], 0, 0, 0);
                }
        }
    }
    // epilogue: D mapping col=lane&15, row=(lane>>4)*4+reg (m89-verified)
#pragma unroll
    for (int fm = 0; fm < 4; ++fm) {
        int grb = m0 + wr * 64 + fm * 16 + lk * 4;
#pragma unroll
        for (int j = 0; j < 4; ++j) {
            int gr = grb + j;
            if (gr >= M) continue;
            float rs = rowscale ? rowscale[gr] : 1.0f;
#pragma unroll
            for (int fn = 0; fn < 4; ++fn) {
                int gc = n0 + wc * 64 + fn * 16 + lr;
                float v = acc[fm][fn][j];
                if (bias) v += rs * bias[gc];
                if (do_relu) v = fmaxf(v, 0.f);
                C[(size_t)gr * Nc + gc] = v;
            }
        }
    }
}

// ---------------------------------------------------------------------------
// Relation attention + combine: block per node, 256 threads (one per channel)
__global__ void attn_combine(const float* __restrict__ msgs,
                             const float* __restrict__ q,
                             ushort_t* __restrict__ s_hi, ushort_t* __restrict__ s_lo,
                             int N) {
    int n = blockIdx.x, j = threadIdx.x;
    size_t NH = (size_t)N * 256;
    size_t base = (size_t)n * 256 + j;
    float m0 = msgs[0 * NH + base];
    float m1 = msgs[1 * NH + base];
    float m2 = msgs[2 * NH + base];
    float m3 = msgs[3 * NH + base];
    float qv = q[j];
    float v0 = m0 * qv, v1 = m1 * qv, v2 = m2 * qv, v3 = m3 * qv;
#pragma unroll
    for (int off = 32; off; off >>= 1) {
        v0 += __shfl_xor(v0, off);
        v1 += __shfl_xor(v1, off);
        v2 += __shfl_xor(v2, off);
        v3 += __shfl_xor(v3, off);
    }
    __shared__ float part[4][4];
    __shared__ float alpha[4];
    int wid = j >> 6, lane = j & 63;
    if (lane == 0) {
        part[0][wid] = v0; part[1][wid] = v1; part[2][wid] = v2; part[3][wid] = v3;
    }
    __syncthreads();
    if (j == 0) {
        float d[4];
#pragma unroll
        for (int r = 0; r < 4; ++r) d[r] = part[r][0] + part[r][1] + part[r][2] + part[r][3];
        float mx = fmaxf(fmaxf(d[0], d[1]), fmaxf(d[2], d[3]));
        float e[4], sum = 0.f;
#pragma unroll
        for (int r = 0; r < 4; ++r) { e[r] = expf(d[r] - mx); sum += e[r]; }
#pragma unroll
        for (int r = 0; r < 4; ++r) alpha[r] = e[r] / sum;
    }
    __syncthreads();
    float sv = alpha[0] * m0 + alpha[1] * m1 + alpha[2] * m2 + alpha[3] * m3;
    sv = fmaxf(sv, 0.f);
    ushort_t h, l;
    bsplit(sv, h, l);
    s_hi[base] = h;
    s_lo[base] = l;
}

// ---------------------------------------------------------------------------
// GRU gate fuse (float4-vectorized): h = (1-z)*n + z*h; emit bf16 hi/lo of h
__global__ void gru_gate(const float* __restrict__ gi, const float* __restrict__ gh,
                         float* __restrict__ h,
                         ushort_t* __restrict__ h_hi, ushort_t* __restrict__ h_lo,
                         int total4) {
    int idx = blockIdx.x * blockDim.x + threadIdx.x;
    if (idx >= total4) return;
    int i = idx >> 6, j = (idx & 63) * 4;
    size_t b = (size_t)i * 768 + j;
    float4 ir = *(const float4*)(gi + b);
    float4 iz = *(const float4*)(gi + b + 256);
    float4 in_ = *(const float4*)(gi + b + 512);
    float4 hr = *(const float4*)(gh + b);
    float4 hz = *(const float4*)(gh + b + 256);
    float4 hn = *(const float4*)(gh + b + 512);
    size_t o = (size_t)i * 256 + j;
    float4 hv = *(const float4*)(h + o);
    float4 hnew;
    const float* irp = &ir.x; const float* izp = &iz.x; const float* inp = &in_.x;
    const float* hrp = &hr.x; const float* hzp = &hz.x; const float* hnp = &hn.x;
    const float* hvp = &hv.x; float* hop = &hnew.x;
    ushort4 hh4, hl4;
    ushort_t* hhp = &hh4.x; ushort_t* hlp = &hl4.x;
#pragma unroll
    for (int k = 0; k < 4; ++k) {
        float r = 1.f / (1.f + expf(-(irp[k] + hrp[k])));
        float z = 1.f / (1.f + expf(-(izp[k] + hzp[k])));
        float ng = tanhf(inp[k] + r * hnp[k]);
        float v = (1.f - z) * ng + z * hvp[k];
        hop[k] = v;
        bsplit(v, hhp[k], hlp[k]);
    }
    *(float4*)(h + o) = hnew;
    *(ushort4*)(h_hi + o) = hh4;
    *(ushort4*)(h_lo + o) = hl4;
}

// ---------------------------------------------------------------------------
// out[n] = dot(h1[n,:], W2[:,0]) + b2[0]
__global__ void classifier_out(const float* __restrict__ h1, const float* __restrict__ W2,
                               const float* __restrict__ b2, float* __restrict__ out, int N) {
    int n = blockIdx.x, j = threadIdx.x;
    float v = h1[(size_t)n * 256 + j] * W2[j];
#pragma unroll
    for (int off = 32; off; off >>= 1) v += __shfl_xor(v, off);
    __shared__ float part[4];
    if ((j & 63) == 0) part[j >> 6] = v;
    __syncthreads();
    if (j == 0) out[n] = part[0] + part[1] + part[2] + part[3] + b2[0];
}

// ---------------------------------------------------------------------------
extern "C" void kernel_launch(void* const* d_in, const int* in_sizes, int n_in,
                              void* d_out, int out_size, void* d_ws, size_t ws_size,
                              hipStream_t stream) {
    const float* feat  = (const float*)d_in[0];
    const int*   erow  = (const int*)d_in[1];
    const int*   ecol  = (const int*)d_in[2];
    const float* ew    = (const float*)d_in[3];
    const float* W_rel = (const float*)d_in[4];
    const float* b_rel = (const float*)d_in[5];
    const float* rq    = (const float*)d_in[6];
    const float* Wih   = (const float*)d_in[7];
    const float* Whh   = (const float*)d_in[8];
    const float* bih   = (const float*)d_in[9];
    const float* bhh   = (const float*)d_in[10];
    const float* W1    = (const float*)d_in[11];
    const float* b1    = (const float*)d_in[12];
    const float* W2    = (const float*)d_in[13];
    const float* b2    = (const float*)d_in[14];
    float* out = (float*)d_out;

    const int N = N_NODES;
    char* ws = (char*)d_ws;

    // --- workspace layout (bytes, 16B aligned; total ~889 MB) ---
    size_t off_msgs   = 0;            // [4][N][256] f32 = 204,800,000 ; aliases gi [N][768], h1
    size_t off_tmp    = 204800000;    // tmp_hi [4][MPAD][256] bf16 = 102,498,304
    size_t off_tmplo  = 307298304;    // tmp_lo 102,498,304 ; gh [N][768] f32 aliases off_tmp
    size_t off_colw   = 409796608;    // [24E] int2 = 153,600,000
    size_t off_h      = 563396608;    // [N][256] f32 = 51,200,000
    size_t off_hhi    = 614596608;    // MPAD*256*2 = 25,624,576
    size_t off_hlo    = 640221184;    // 25,624,576
    size_t off_shi    = 665845760;    // 25,624,576
    size_t off_slo    = 691470336;    // 25,624,576
    size_t off_rowsum = 717094912;    // [4][MPAD] f32 = 800,768
    size_t off_wrelh  = 717895680;    // 524,288
    size_t off_wrell  = 718419968;    // 524,288
    size_t off_wihh   = 718944256;    // 393,216
    size_t off_wihl   = 719337472;    // 393,216
    size_t off_whhh   = 719730688;    // 393,216
    size_t off_whhl   = 720123904;    // 393,216
    size_t off_w1h    = 720517120;    // 131,072
    size_t off_w1l    = 720648192;    // 131,072
    size_t off_bcnt   = 720779264;    // NBKT_TOT*4 = 75,072
    size_t off_bcur   = 720854336;    // 75,072
    size_t off_bstart = 720929408;    // (NBKT_TOT+1)*4 -> 75,088 (padded)
    size_t off_starts = 730379264;    // (NTOT+1)*4 -> 4,800,016
    size_t off_bsums  = 735179280;    // 8,192
    size_t off_bsumsX = 735187472;    // 8,192
    size_t off_brec   = 735195664;    // [24E] int2 = 153,600,000 (end ~888.8 MB)

    float*    msgs   = (float*)(ws + off_msgs);
    float*    gi     = (float*)(ws + off_msgs);     // alias (msgs dead)
    float*    h1     = (float*)(ws + off_msgs);     // alias (gi dead)
    ushort_t* tmp_hi = (ushort_t*)(ws + off_tmp);
    ushort_t* tmp_lo = (ushort_t*)(ws + off_tmplo);
    float*    gh     = (float*)(ws + off_tmp);      // alias (tmp dead when gh written)
    int2*     colw   = (int2*)(ws + off_colw);
    float*    h      = (float*)(ws + off_h);
    ushort_t* h_hi   = (ushort_t*)(ws + off_hhi);
    ushort_t* h_lo   = (ushort_t*)(ws + off_hlo);
    ushort_t* s_hi   = (ushort_t*)(ws + off_shi);
    ushort_t* s_lo   = (ushort_t*)(ws + off_slo);
    float*    rowsum = (float*)(ws + off_rowsum);
    ushort_t* wrel_h = (ushort_t*)(ws + off_wrelh);
    ushort_t* wrel_l = (ushort_t*)(ws + off_wrell);
    ushort_t* wih_h  = (ushort_t*)(ws + off_wihh);
    ushort_t* wih_l  = (ushort_t*)(ws + off_wihl);
    ushort_t* whh_h  = (ushort_t*)(ws + off_whhh);
    ushort_t* whh_l  = (ushort_t*)(ws + off_whhl);
    ushort_t* w1_h   = (ushort_t*)(ws + off_w1h);
    ushort_t* w1_l   = (ushort_t*)(ws + off_w1l);
    int*      bcnt   = (int*)(ws + off_bcnt);
    int*      bcur   = (int*)(ws + off_bcur);
    int*      bstarts= (int*)(ws + off_bstart);
    int*      starts = (int*)(ws + off_starts);
    int*      bsums  = (int*)(ws + off_bsums);
    int*      bsumsX = (int*)(ws + off_bsumsX);
    int2*     brec   = (int2*)(ws + off_brec);

    const int NB_SCAN = (NBKT_TOT + 1023) / 1024;   // 19

    // one-time prep: weights -> bf16 hi/lo B^T
    for (int r = 0; r < R_REL; ++r)
        prep_bt<<<(65536 + 255) / 256, 256, 0, stream>>>(
            W_rel + (size_t)r * 65536, wrel_h + (size_t)r * 65536,
            wrel_l + (size_t)r * 65536, 256, 256, 0);
    prep_bt<<<(G3 * 256 + 255) / 256, 256, 0, stream>>>(Wih, wih_h, wih_l, 256, G3, 1);
    prep_bt<<<(G3 * 256 + 255) / 256, 256, 0, stream>>>(Whh, whh_h, whh_l, 256, G3, 1);
    prep_bt<<<(65536 + 255) / 256, 256, 0, stream>>>(W1, w1_h, w1_l, 256, 256, 0);

    hipMemsetAsync(h, 0, (size_t)N * HID * 4, stream);
    hipMemsetAsync(ws + off_hhi, 0, 2 * 25624576, stream);       // h_hi + h_lo
    hipMemsetAsync(bcnt, 0, 2 * 75072, stream);                  // bcnt + bcur

    // bucketed CSR build for all 24 (t,r) graphs
    int eblocks = (ETOT + 255) / 256;
    bucket_hist<<<eblocks, 256, 0, stream>>>(erow, bcnt);
    scan1<<<NB_SCAN, 1024, 0, stream>>>(bcnt, bstarts, bsums, NBKT_TOT);
    scan_block<<<1, 1024, 0, stream>>>(bsums, bsumsX, NB_SCAN);
    scan3<<<NB_SCAN, 1024, 0, stream>>>(bstarts, bsumsX, NBKT_TOT);
    bucket_fill<<<eblocks, 256, 0, stream>>>(erow, ecol, ew, bstarts, bcur, brec);
    csr_place<<<NBKT_TOT, 256, 0, stream>>>(brec, bstarts, starts, colw);

    dim3 g_rel(MPAD / 128, 2, 4);   // 4 relations, Nc=256
    dim3 g_g3(MPAD / 128, 6, 1);    // Nc=768
    dim3 g_cls(MPAD / 128, 2, 1);
    dim3 agg_grid((N + 3) / 4, 4);  // 4 waves/block, one wave per row; y = relation

    for (int t = 0; t < T_STEPS; ++t) {
        const float* x_t = feat + (size_t)t * N * IN_DIM;
        csr_agg_t<<<agg_grid, 256, 0, stream>>>(
            x_t, colw, starts + (size_t)t * R_REL * N, tmp_hi, tmp_lo, rowsum);
        mfma_gemm<<<g_rel, 256, 0, stream>>>(
            tmp_hi, tmp_lo, wrel_h, wrel_l, msgs, N, 256, b_rel, rowsum, 0,
            (size_t)MPAD * 256, 65536, (size_t)N * 256, 256, MPAD);
        attn_combine<<<N, 256, 0, stream>>>(msgs, rq, s_hi, s_lo, N);
        mfma_gemm<<<g_g3, 256, 0, stream>>>(s_hi, s_lo, wih_h, wih_l, gi, N, G3,
                                            bih, nullptr, 0, 0, 0, 0, 0, 0);
        mfma_gemm<<<g_g3, 256, 0, stream>>>(h_hi, h_lo, whh_h, whh_l, gh, N, G3,
                                            bhh, nullptr, 0, 0, 0, 0, 0, 0);
        gru_gate<<<(N * 64 + 255) / 256, 256, 0, stream>>>(gi, gh, h, h_hi, h_lo, N * 64);
    }

    // classifier
    mfma_gemm<<<g_cls, 256, 0, stream>>>(h_hi, h_lo, w1_h, w1_l, h1, N, 256,
                                         b1, nullptr, 1, 0, 0, 0, 0, 0);
    classifier_out<<<N, 256, 0, stream>>>(h1, W2, b2, out, N);
}

// Round 6
// 7842.912 us; speedup vs baseline: 1.1996x; 1.1996x over previous
//
#include <hip/hip_runtime.h>
#include <hip/hip_bf16.h>
#include <math.h>

// Problem constants (fixed by the reference)
#define T_STEPS 6
#define N_NODES 50000
#define IN_DIM  256
#define HID     256
#define R_REL   4
#define E_EDGES 800000
#define G3      768    // 3*HID
#define MPAD    50048  // N rounded up to 128
#define NTR     24     // T*R
#define ETOT    19200000
#define NTOT    1200000   // NTR*N
#define NB8_R   6250      // 50000/8 buckets of 8 rows per (t,r)
#define NB8_TOT 150000    // NB8_R * NTR
#define NXP     8         // xcd partitions

typedef unsigned short ushort_t;
typedef __bf16 bf16x8 __attribute__((ext_vector_type(8)));
typedef float  f32x4  __attribute__((ext_vector_type(4)));

// round-to-nearest-even fp32 -> bf16 (bit-level, self-contained)
__device__ __forceinline__ ushort_t f2bf(float f) {
    unsigned u = __float_as_uint(f);
    u = (u + 0x7FFF + ((u >> 16) & 1)) >> 16;
    return (ushort_t)u;
}
__device__ __forceinline__ float bf2f(ushort_t b) {
    return __uint_as_float(((unsigned)b) << 16);
}
__device__ __forceinline__ void bsplit(float v, ushort_t& h, ushort_t& l) {
    h = f2bf(v);
    l = f2bf(v - bf2f(h));
}

// ---------------------------------------------------------------------------
// Weight prep: dst (hi/lo bf16, [Nc][K] row-major = B^T) from fp32 src.
__global__ void prep_bt(const float* __restrict__ src, ushort_t* __restrict__ hi,
                        ushort_t* __restrict__ lo, int K, int Nc, int transposed) {
    int idx = blockIdx.x * blockDim.x + threadIdx.x;
    if (idx >= K * Nc) return;
    int n = idx / K, k = idx % K;
    float v = transposed ? src[(size_t)n * K + k] : src[(size_t)k * Nc + n];
    ushort_t h, l;
    bsplit(v, h, l);
    hi[idx] = h;
    lo[idx] = l;
}

// ---------------------------------------------------------------------------
// XCD-partitioned bucketed CSR build. Bucket = (tr, row>>3); 8 rows each.
// Records for bucket b are stored as 8 contiguous per-partition sub-lists, so
// every brec cache line is written by (mostly) one XCD -> no line ping-pong.

// Step 1: per-(partition, bucket) histogram, partition-major layout.
__global__ void hist2(const int* __restrict__ row, int* __restrict__ counts2) {
    int ge = blockIdx.x * blockDim.x + threadIdx.x;
    if (ge >= ETOT) return;
    int xcd = blockIdx.x & (NXP - 1);
    int tr = ge / E_EDGES;
    atomicAdd(&counts2[xcd * NB8_TOT + tr * NB8_R + (row[ge] >> 3)], 1);
}

// scan step 1: per-block (1024) exclusive scan over bucket-major order
// (i = b*8 + x reads counts2[x*NB8_TOT + b]); emit block sums
__global__ __launch_bounds__(1024)
void scan1(const int* __restrict__ counts2, int* __restrict__ bxstarts,
           int* __restrict__ bsums, int n) {
    __shared__ int temp[1024];
    int i = blockIdx.x * 1024 + threadIdx.x;
    int v = (i < n) ? counts2[(i & 7) * NB8_TOT + (i >> 3)] : 0;
    temp[threadIdx.x] = v;
    __syncthreads();
#pragma unroll
    for (int off = 1; off < 1024; off <<= 1) {
        int t = (threadIdx.x >= (unsigned)off) ? temp[threadIdx.x - off] : 0;
        __syncthreads();
        temp[threadIdx.x] += t;
        __syncthreads();
    }
    int incl = temp[threadIdx.x];
    if (i < n) bxstarts[i] = incl - v;
    if (threadIdx.x == 1023) bsums[blockIdx.x] = incl;
}

// scan step 2: single-block exclusive scan of block sums
__global__ __launch_bounds__(1024)
void scan_block(const int* __restrict__ counts, int* __restrict__ starts, int n) {
    __shared__ int temp[1024];
    __shared__ int carry;
    if (threadIdx.x == 0) carry = 0;
    __syncthreads();
    for (int base = 0; base < n; base += 1024) {
        int i = base + (int)threadIdx.x;
        int v = (i < n) ? counts[i] : 0;
        temp[threadIdx.x] = v;
        __syncthreads();
#pragma unroll
        for (int off = 1; off < 1024; off <<= 1) {
            int t = (threadIdx.x >= (unsigned)off) ? temp[threadIdx.x - off] : 0;
            __syncthreads();
            temp[threadIdx.x] += t;
            __syncthreads();
        }
        int incl = temp[threadIdx.x];
        if (i < n) starts[i] = carry + incl - v;
        __syncthreads();
        if (threadIdx.x == 1023) carry += incl;
        __syncthreads();
    }
    if (threadIdx.x == 0) starts[n] = carry;
}

// scan step 3: add block offsets; write sentinel
__global__ __launch_bounds__(1024)
void scan3(int* __restrict__ starts, const int* __restrict__ bsumsX, int n) {
    int i = blockIdx.x * 1024 + threadIdx.x;
    if (i < n) starts[i] += bsumsX[blockIdx.x];
    if (i == 0) starts[n] = ETOT;
}

// Step 2: scatter packed records into (bucket, partition)-sorted order.
// Cursor atomics stay within one partition region (same-XCD L2, fast);
// data writes land in per-partition sub-runs (single-XCD lines).
__global__ void fill2(const int* __restrict__ row, const int* __restrict__ col,
                      const float* __restrict__ w, const int* __restrict__ bxstarts,
                      int* __restrict__ cur2, int2* __restrict__ brec) {
    int ge = blockIdx.x * blockDim.x + threadIdx.x;
    if (ge >= ETOT) return;
    int xcd = blockIdx.x & (NXP - 1);
    int tr = ge / E_EDGES;
    int rr = row[ge];
    int b = tr * NB8_R + (rr >> 3);
    int pos = bxstarts[b * 8 + xcd] + atomicAdd(&cur2[xcd * NB8_TOT + b], 1);
    brec[pos] = make_int2(col[ge] | ((rr & 7) << 16), __float_as_int(w[ge]));
}

// Step 3: one block per 32 buckets. LDS row-count + prefix -> write exact
// per-row starts[] (replaces a row-level hist+scan), then re-scatter records
// into final CSR order (writes in ~1KB windows, single-block -> line-local).
__global__ __launch_bounds__(256)
void place8(const int2* __restrict__ brec, const int* __restrict__ bxstarts,
            int* __restrict__ starts, int2* __restrict__ colw) {
    __shared__ int cnt[256], rst[256];
    int tid = threadIdx.x;
    int B0 = blockIdx.x * 32;
    cnt[tid] = 0;
    if (tid == 0 && blockIdx.x == 0) starts[NTOT] = ETOT;
    __syncthreads();
    // count pass (counters disjoint per bucket -> no syncs inside loop)
    for (int bi = 0; bi < 32; ++bi) {
        int b = B0 + bi;
        if (b >= NB8_TOT) break;
        int s0 = bxstarts[b * 8], s1 = bxstarts[b * 8 + 8];
        for (int e = s0 + tid; e < s1; e += 256)
            atomicAdd(&cnt[bi * 8 + ((brec[e].x >> 16) & 7)], 1);
    }
    __syncthreads();
    if (tid < 32) {
        int run = 0;
#pragma unroll
        for (int j = 0; j < 8; ++j) { rst[tid * 8 + j] = run; run += cnt[tid * 8 + j]; }
    }
    __syncthreads();
    {   // write row-level starts
        int bi = tid >> 3, j = tid & 7;
        int b = B0 + bi;
        if (b < NB8_TOT) {
            int tr = b / NB8_R, r0 = (b % NB8_R) * 8 + j;
            starts[tr * N_NODES + r0] = bxstarts[b * 8] + rst[tid];
        }
    }
    cnt[tid] = 0;
    __syncthreads();
    // scatter pass
    for (int bi = 0; bi < 32; ++bi) {
        int b = B0 + bi;
        if (b >= NB8_TOT) break;
        int s0 = bxstarts[b * 8], s1 = bxstarts[b * 8 + 8];
        for (int e = s0 + tid; e < s1; e += 256) {
            int2 rec = brec[e];
            int rl = (rec.x >> 16) & 7;
            int pos = s0 + rst[bi * 8 + rl] + atomicAdd(&cnt[bi * 8 + rl], 1);
            colw[pos] = make_int2(rec.x & 0xFFFF, rec.y);
        }
    }
}

// ---------------------------------------------------------------------------
// Aggregation, batched over the 4 relations of one t (blockIdx.y = r).
// One wave per destination row; gather x rows, accumulate, write bf16 hi/lo.
__global__ void csr_agg_t(const float* __restrict__ x, const int2* __restrict__ colw,
                          const int* __restrict__ startsT,
                          ushort_t* __restrict__ tmp_hi, ushort_t* __restrict__ tmp_lo,
                          float* __restrict__ rowsum) {
    int wid  = (blockIdx.x * blockDim.x + threadIdx.x) >> 6;
    int lane = threadIdx.x & 63;
    int r    = blockIdx.y;
    if (wid >= N_NODES) return;
    int s0 = startsT[r * N_NODES + wid], s1 = startsT[r * N_NODES + wid + 1];
    float4 acc = make_float4(0.f, 0.f, 0.f, 0.f);
    float wsum = 0.f;
    for (int e = s0; e < s1; ++e) {
        int2 cw = colw[e];
        float we = __int_as_float(cw.y);
        float4 xv = ((const float4*)(x + (size_t)cw.x * 256))[lane];
        acc.x = fmaf(we, xv.x, acc.x);
        acc.y = fmaf(we, xv.y, acc.y);
        acc.z = fmaf(we, xv.z, acc.z);
        acc.w = fmaf(we, xv.w, acc.w);
        wsum += we;
    }
    ushort4 hv, lv;
    bsplit(acc.x, hv.x, lv.x);
    bsplit(acc.y, hv.y, lv.y);
    bsplit(acc.z, hv.z, lv.z);
    bsplit(acc.w, hv.w, lv.w);
    size_t o = ((size_t)r * MPAD + wid) * 256 + lane * 4;
    *(ushort4*)(tmp_hi + o) = hv;
    *(ushort4*)(tmp_lo + o) = lv;
    if (lane == 0) rowsum[r * MPAD + wid] = wsum;
}

// ---------------------------------------------------------------------------
// MFMA GEMM, hi/lo split: C = (Ahi+Alo) @ (Bhi+Blo), dropping lo*lo.
// A row-major [M][256] bf16; B transposed [Nc][256] bf16.
// Tile 128x128, BK=64, 4 waves (2x2). blockIdx.z selects batched operand set.
__global__ __launch_bounds__(256, 2)
void mfma_gemm(const ushort_t* __restrict__ Ahi, const ushort_t* __restrict__ Alo,
               const ushort_t* __restrict__ Bthi, const ushort_t* __restrict__ Btlo,
               float* __restrict__ C, int M, int Nc,
               const float* __restrict__ bias, const float* __restrict__ rowscale,
               int do_relu, size_t aZ, size_t bZ, size_t cZ, int biasZ, int rsZ) {
    int z = blockIdx.z;
    Ahi  += (size_t)z * aZ;  Alo  += (size_t)z * aZ;
    Bthi += (size_t)z * bZ;  Btlo += (size_t)z * bZ;
    C    += (size_t)z * cZ;
    if (bias)     bias     += (size_t)z * biasZ;
    if (rowscale) rowscale += (size_t)z * rsZ;

    __shared__ __align__(16) char smem[65536];
    const int AHI = 0, ALO = 16384, BHI = 32768, BLO = 49152;
    int tid = threadIdx.x;
    int m0 = blockIdx.x * 128, n0 = blockIdx.y * 128;
    int lane = tid & 63, wid = tid >> 6;
    int wr = wid >> 1, wc = wid & 1;
    int lr = lane & 15, lk = lane >> 4;
    int xorv = (lr & 7) << 4;

    f32x4 acc[4][4];
#pragma unroll
    for (int i = 0; i < 4; ++i)
#pragma unroll
        for (int j = 0; j < 4; ++j)
            acc[i][j] = (f32x4){0.f, 0.f, 0.f, 0.f};

    for (int kt = 0; kt < 4; ++kt) {
        int k0 = kt * 64;
        __syncthreads();
#pragma unroll
        for (int i = 0; i < 4; ++i) {
            int c = tid + i * 256;          // 0..1023 chunk id (16B chunks)
            int row = c >> 3, slot = c & 7; // 128 rows x 8 slots
            int ldsoff = row * 128 + ((slot * 16) ^ ((row & 7) << 4));
            size_t ga = (size_t)(m0 + row) * 256 + k0 + slot * 8;
            size_t gb = (size_t)(n0 + row) * 256 + k0 + slot * 8;
            *(int4*)(smem + AHI + ldsoff) = *(const int4*)(Ahi + ga);
            *(int4*)(smem + ALO + ldsoff) = *(const int4*)(Alo + ga);
            *(int4*)(smem + BHI + ldsoff) = *(const int4*)(Bthi + gb);
            *(int4*)(smem + BLO + ldsoff) = *(const int4*)(Btlo + gb);
        }
        __syncthreads();
#pragma unroll
        for (int kk2 = 0; kk2 < 2; ++kk2) {
            int kb = (kk2 * 64 + lk * 16) ^ xorv;
            bf16x8 ah[4], al[4], bh[4], bl[4];
#pragma unroll
            for (int f = 0; f < 4; ++f) {
                int ra = (wr * 64 + f * 16 + lr) * 128 + kb;
                int rb = (wc * 64 + f * 16 + lr) * 128 + kb;
                ah[f] = *(const bf16x8*)(smem + AHI + ra);
                al[f] = *(const bf16x8*)(smem + ALO + ra);
                bh[f] = *(const bf16x8*)(smem + BHI + rb);
                bl[f] = *(const bf16x8*)(smem + BLO + rb);
            }
#pragma unroll
            for (int fm = 0; fm < 4; ++fm)
#pragma unroll
                for (int fn = 0; fn < 4; ++fn) {
                    acc[fm][fn] = __builtin_amdgcn_mfma_f32_16x16x32_bf16(ah[fm], bh[fn], acc[fm][fn], 0, 0, 0);
                    acc[fm][fn] = __builtin_amdgcn_mfma_f32_16x16x32_bf16(ah[fm], bl[fn], acc[fm][fn], 0, 0, 0);
                    acc[fm][fn] = __builtin_amdgcn_mfma_f32_16x16x32_bf16(al[fm], bh[fn], acc[fm][fn], 0, 0, 0);
                }
        }
    }
    // epilogue: D mapping col=lane&15, row=(lane>>4)*4+reg (m89-verified)
#pragma unroll
    for (int fm = 0; fm < 4; ++fm) {
        int grb = m0 + wr * 64 + fm * 16 + lk * 4;
#pragma unroll
        for (int j = 0; j < 4; ++j) {
            int gr = grb + j;
            if (gr >= M) continue;
            float rs = rowscale ? rowscale[gr] : 1.0f;
#pragma unroll
            for (int fn = 0; fn < 4; ++fn) {
                int gc = n0 + wc * 64 + fn * 16 + lr;
                float v = acc[fm][fn][j];
                if (bias) v += rs * bias[gc];
                if (do_relu) v = fmaxf(v, 0.f);
                C[(size_t)gr * Nc + gc] = v;
            }
        }
    }
}

// ---------------------------------------------------------------------------
// Relation attention + combine: block per node, 256 threads (one per channel)
__global__ void attn_combine(const float* __restrict__ msgs,
                             const float* __restrict__ q,
                             ushort_t* __restrict__ s_hi, ushort_t* __restrict__ s_lo,
                             int N) {
    int n = blockIdx.x, j = threadIdx.x;
    size_t NH = (size_t)N * 256;
    size_t base = (size_t)n * 256 + j;
    float m0 = msgs[0 * NH + base];
    float m1 = msgs[1 * NH + base];
    float m2 = msgs[2 * NH + base];
    float m3 = msgs[3 * NH + base];
    float qv = q[j];
    float v0 = m0 * qv, v1 = m1 * qv, v2 = m2 * qv, v3 = m3 * qv;
#pragma unroll
    for (int off = 32; off; off >>= 1) {
        v0 += __shfl_xor(v0, off);
        v1 += __shfl_xor(v1, off);
        v2 += __shfl_xor(v2, off);
        v3 += __shfl_xor(v3, off);
    }
    __shared__ float part[4][4];
    __shared__ float alpha[4];
    int wid = j >> 6, lane = j & 63;
    if (lane == 0) {
        part[0][wid] = v0; part[1][wid] = v1; part[2][wid] = v2; part[3][wid] = v3;
    }
    __syncthreads();
    if (j == 0) {
        float d[4];
#pragma unroll
        for (int r = 0; r < 4; ++r) d[r] = part[r][0] + part[r][1] + part[r][2] + part[r][3];
        float mx = fmaxf(fmaxf(d[0], d[1]), fmaxf(d[2], d[3]));
        float e[4], sum = 0.f;
#pragma unroll
        for (int r = 0; r < 4; ++r) { e[r] = expf(d[r] - mx); sum += e[r]; }
#pragma unroll
        for (int r = 0; r < 4; ++r) alpha[r] = e[r] / sum;
    }
    __syncthreads();
    float sv = alpha[0] * m0 + alpha[1] * m1 + alpha[2] * m2 + alpha[3] * m3;
    sv = fmaxf(sv, 0.f);
    ushort_t h, l;
    bsplit(sv, h, l);
    s_hi[base] = h;
    s_lo[base] = l;
}

// ---------------------------------------------------------------------------
// GRU gate fuse (float4-vectorized): h = (1-z)*n + z*h; emit bf16 hi/lo of h
__global__ void gru_gate(const float* __restrict__ gi, const float* __restrict__ gh,
                         float* __restrict__ h,
                         ushort_t* __restrict__ h_hi, ushort_t* __restrict__ h_lo,
                         int total4) {
    int idx = blockIdx.x * blockDim.x + threadIdx.x;
    if (idx >= total4) return;
    int i = idx >> 6, j = (idx & 63) * 4;
    size_t b = (size_t)i * 768 + j;
    float4 ir = *(const float4*)(gi + b);
    float4 iz = *(const float4*)(gi + b + 256);
    float4 in_ = *(const float4*)(gi + b + 512);
    float4 hr = *(const float4*)(gh + b);
    float4 hz = *(const float4*)(gh + b + 256);
    float4 hn = *(const float4*)(gh + b + 512);
    size_t o = (size_t)i * 256 + j;
    float4 hv = *(const float4*)(h + o);
    float4 hnew;
    const float* irp = &ir.x; const float* izp = &iz.x; const float* inp = &in_.x;
    const float* hrp = &hr.x; const float* hzp = &hz.x; const float* hnp = &hn.x;
    const float* hvp = &hv.x; float* hop = &hnew.x;
    ushort4 hh4, hl4;
    ushort_t* hhp = &hh4.x; ushort_t* hlp = &hl4.x;
#pragma unroll
    for (int k = 0; k < 4; ++k) {
        float r = 1.f / (1.f + expf(-(irp[k] + hrp[k])));
        float z = 1.f / (1.f + expf(-(izp[k] + hzp[k])));
        float ng = tanhf(inp[k] + r * hnp[k]);
        float v = (1.f - z) * ng + z * hvp[k];
        hop[k] = v;
        bsplit(v, hhp[k], hlp[k]);
    }
    *(float4*)(h + o) = hnew;
    *(ushort4*)(h_hi + o) = hh4;
    *(ushort4*)(h_lo + o) = hl4;
}

// ---------------------------------------------------------------------------
// out[n] = dot(h1[n,:], W2[:,0]) + b2[0]
__global__ void classifier_out(const float* __restrict__ h1, const float* __restrict__ W2,
                               const float* __restrict__ b2, float* __restrict__ out, int N) {
    int n = blockIdx.x, j = threadIdx.x;
    float v = h1[(size_t)n * 256 + j] * W2[j];
#pragma unroll
    for (int off = 32; off; off >>= 1) v += __shfl_xor(v, off);
    __shared__ float part[4];
    if ((j & 63) == 0) part[j >> 6] = v;
    __syncthreads();
    if (j == 0) out[n] = part[0] + part[1] + part[2] + part[3] + b2[0];
}

// ---------------------------------------------------------------------------
extern "C" void kernel_launch(void* const* d_in, const int* in_sizes, int n_in,
                              void* d_out, int out_size, void* d_ws, size_t ws_size,
                              hipStream_t stream) {
    const float* feat  = (const float*)d_in[0];
    const int*   erow  = (const int*)d_in[1];
    const int*   ecol  = (const int*)d_in[2];
    const float* ew    = (const float*)d_in[3];
    const float* W_rel = (const float*)d_in[4];
    const float* b_rel = (const float*)d_in[5];
    const float* rq    = (const float*)d_in[6];
    const float* Wih   = (const float*)d_in[7];
    const float* Whh   = (const float*)d_in[8];
    const float* bih   = (const float*)d_in[9];
    const float* bhh   = (const float*)d_in[10];
    const float* W1    = (const float*)d_in[11];
    const float* b1    = (const float*)d_in[12];
    const float* W2    = (const float*)d_in[13];
    const float* b2    = (const float*)d_in[14];
    float* out = (float*)d_out;

    const int N = N_NODES;
    char* ws = (char*)d_ws;

    // --- workspace layout (bytes, 16B aligned; total ~894 MB) ---
    size_t off_msgs   = 0;            // [4][N][256] f32 = 204,800,000 ; aliases gi [N][768], h1
    size_t off_tmp    = 204800000;    // tmp_hi [4][MPAD][256] bf16 = 102,498,304
    size_t off_tmplo  = 307298304;    // tmp_lo 102,498,304 ; gh [N][768] f32 aliases off_tmp
    size_t off_colw   = 409796608;    // [24E] int2 = 153,600,000
    size_t off_h      = 563396608;    // [N][256] f32 = 51,200,000
    size_t off_hhi    = 614596608;    // MPAD*256*2 = 25,624,576
    size_t off_hlo    = 640221184;    // 25,624,576
    size_t off_shi    = 665845760;    // 25,624,576
    size_t off_slo    = 691470336;    // 25,624,576
    size_t off_rowsum = 717094912;    // [4][MPAD] f32 = 800,768
    size_t off_wrelh  = 717895680;    // 524,288
    size_t off_wrell  = 718419968;    // 524,288
    size_t off_wihh   = 718944256;    // 393,216
    size_t off_wihl   = 719337472;    // 393,216
    size_t off_whhh   = 719730688;    // 393,216
    size_t off_whhl   = 720123904;    // 393,216
    size_t off_w1h    = 720517120;    // 131,072
    size_t off_w1l    = 720648192;    // 131,072
    size_t off_cnt2   = 720779264;    // [8][NB8_TOT] = 4,800,000
    size_t off_cur2   = 725579264;    // [8][NB8_TOT] = 4,800,000
    size_t off_starts = 730379264;    // (NTOT+1)*4 -> 4,800,016
    size_t off_bxst   = 735179280;    // (NTOT+1)*4 -> 4,800,016
    size_t off_bsums  = 739979296;    // 8,192
    size_t off_bsumsX = 739987488;    // 8,192
    size_t off_brec   = 739995680;    // [24E] int2 = 153,600,000 (end ~893.6 MB)

    float*    msgs   = (float*)(ws + off_msgs);
    float*    gi     = (float*)(ws + off_msgs);     // alias (msgs dead)
    float*    h1     = (float*)(ws + off_msgs);     // alias (gi dead)
    ushort_t* tmp_hi = (ushort_t*)(ws + off_tmp);
    ushort_t* tmp_lo = (ushort_t*)(ws + off_tmplo);
    float*    gh     = (float*)(ws + off_tmp);      // alias (tmp dead when gh written)
    int2*     colw   = (int2*)(ws + off_colw);
    float*    h      = (float*)(ws + off_h);
    ushort_t* h_hi   = (ushort_t*)(ws + off_hhi);
    ushort_t* h_lo   = (ushort_t*)(ws + off_hlo);
    ushort_t* s_hi   = (ushort_t*)(ws + off_shi);
    ushort_t* s_lo   = (ushort_t*)(ws + off_slo);
    float*    rowsum = (float*)(ws + off_rowsum);
    ushort_t* wrel_h = (ushort_t*)(ws + off_wrelh);
    ushort_t* wrel_l = (ushort_t*)(ws + off_wrell);
    ushort_t* wih_h  = (ushort_t*)(ws + off_wihh);
    ushort_t* wih_l  = (ushort_t*)(ws + off_wihl);
    ushort_t* whh_h  = (ushort_t*)(ws + off_whhh);
    ushort_t* whh_l  = (ushort_t*)(ws + off_whhl);
    ushort_t* w1_h   = (ushort_t*)(ws + off_w1h);
    ushort_t* w1_l   = (ushort_t*)(ws + off_w1l);
    int*      cnt2   = (int*)(ws + off_cnt2);
    int*      cur2   = (int*)(ws + off_cur2);
    int*      starts = (int*)(ws + off_starts);
    int*      bxst   = (int*)(ws + off_bxst);
    int*      bsums  = (int*)(ws + off_bsums);
    int*      bsumsX = (int*)(ws + off_bsumsX);
    int2*     brec   = (int2*)(ws + off_brec);

    const int NB_SCAN = (NTOT + 1023) / 1024;   // 1172

    // one-time prep: weights -> bf16 hi/lo B^T
    for (int r = 0; r < R_REL; ++r)
        prep_bt<<<(65536 + 255) / 256, 256, 0, stream>>>(
            W_rel + (size_t)r * 65536, wrel_h + (size_t)r * 65536,
            wrel_l + (size_t)r * 65536, 256, 256, 0);
    prep_bt<<<(G3 * 256 + 255) / 256, 256, 0, stream>>>(Wih, wih_h, wih_l, 256, G3, 1);
    prep_bt<<<(G3 * 256 + 255) / 256, 256, 0, stream>>>(Whh, whh_h, whh_l, 256, G3, 1);
    prep_bt<<<(65536 + 255) / 256, 256, 0, stream>>>(W1, w1_h, w1_l, 256, 256, 0);

    hipMemsetAsync(h, 0, (size_t)N * HID * 4, stream);
    hipMemsetAsync(ws + off_hhi, 0, 2 * 25624576, stream);       // h_hi + h_lo
    hipMemsetAsync(cnt2, 0, 2 * 4800000, stream);                // cnt2 + cur2

    // XCD-partitioned bucketed CSR build for all 24 (t,r) graphs
    int eblocks = ETOT / 256;   // 75000 exact; 800000 % 256 == 0 -> no tr straddle
    hist2<<<eblocks, 256, 0, stream>>>(erow, cnt2);
    scan1<<<NB_SCAN, 1024, 0, stream>>>(cnt2, bxst, bsums, NTOT);
    scan_block<<<1, 1024, 0, stream>>>(bsums, bsumsX, NB_SCAN);
    scan3<<<NB_SCAN, 1024, 0, stream>>>(bxst, bsumsX, NTOT);
    fill2<<<eblocks, 256, 0, stream>>>(erow, ecol, ew, bxst, cur2, brec);
    place8<<<(NB8_TOT + 31) / 32, 256, 0, stream>>>(brec, bxst, starts, colw);

    dim3 g_rel(MPAD / 128, 2, 4);   // 4 relations, Nc=256
    dim3 g_g3(MPAD / 128, 6, 1);    // Nc=768
    dim3 g_cls(MPAD / 128, 2, 1);
    dim3 agg_grid((N + 3) / 4, 4);  // 4 waves/block, one wave per row; y = relation

    for (int t = 0; t < T_STEPS; ++t) {
        const float* x_t = feat + (size_t)t * N * IN_DIM;
        csr_agg_t<<<agg_grid, 256, 0, stream>>>(
            x_t, colw, starts + (size_t)t * R_REL * N, tmp_hi, tmp_lo, rowsum);
        mfma_gemm<<<g_rel, 256, 0, stream>>>(
            tmp_hi, tmp_lo, wrel_h, wrel_l, msgs, N, 256, b_rel, rowsum, 0,
            (size_t)MPAD * 256, 65536, (size_t)N * 256, 256, MPAD);
        attn_combine<<<N, 256, 0, stream>>>(msgs, rq, s_hi, s_lo, N);
        mfma_gemm<<<g_g3, 256, 0, stream>>>(s_hi, s_lo, wih_h, wih_l, gi, N, G3,
                                            bih, nullptr, 0, 0, 0, 0, 0, 0);
        mfma_gemm<<<g_g3, 256, 0, stream>>>(h_hi, h_lo, whh_h, whh_l, gh, N, G3,
                                            bhh, nullptr, 0, 0, 0, 0, 0, 0);
        gru_gate<<<(N * 64 + 255) / 256, 256, 0, stream>>>(gi, gh, h, h_hi, h_lo, N * 64);
    }

    // classifier
    mfma_gemm<<<g_cls, 256, 0, stream>>>(h_hi, h_lo, w1_h, w1_l, h1, N, 256,
                                         b1, nullptr, 1, 0, 0, 0, 0, 0);
    classifier_out<<<N, 256, 0, stream>>>(h1, W2, b2, out, N);
}